// Round 4
// baseline (277.609 us; speedup 1.0000x reference)
//
#include <hip/hip_runtime.h>

#define N_PTS 32768
#define BATCH 16
#define PIO2F 1.5707963705062866f

// ---------------- repetition macros ----------------
// NOTE: REP16I is an identical copy of REP16 used for INNER loops nested
// inside an outer REP16 expansion (C preprocessor forbids recursive expansion).
#define REP16(M) M(0)M(1)M(2)M(3)M(4)M(5)M(6)M(7)M(8)M(9)M(10)M(11)M(12)M(13)M(14)M(15)
#define REP16I(M) M(0)M(1)M(2)M(3)M(4)M(5)M(6)M(7)M(8)M(9)M(10)M(11)M(12)M(13)M(14)M(15)
#define REP62(M) M(0)M(1)M(2)M(3)M(4)M(5)M(6)M(7)M(8)M(9)M(10)M(11)M(12)M(13)M(14)M(15)\
M(16)M(17)M(18)M(19)M(20)M(21)M(22)M(23)M(24)M(25)M(26)M(27)M(28)M(29)M(30)M(31)\
M(32)M(33)M(34)M(35)M(36)M(37)M(38)M(39)M(40)M(41)M(42)M(43)M(44)M(45)M(46)M(47)\
M(48)M(49)M(50)M(51)M(52)M(53)M(54)M(55)M(56)M(57)M(58)M(59)M(60)M(61)
#define REP100(M) M(0)M(1)M(2)M(3)M(4)M(5)M(6)M(7)M(8)M(9)M(10)M(11)M(12)M(13)M(14)M(15)\
M(16)M(17)M(18)M(19)M(20)M(21)M(22)M(23)M(24)M(25)M(26)M(27)M(28)M(29)M(30)M(31)\
M(32)M(33)M(34)M(35)M(36)M(37)M(38)M(39)M(40)M(41)M(42)M(43)M(44)M(45)M(46)M(47)\
M(48)M(49)M(50)M(51)M(52)M(53)M(54)M(55)M(56)M(57)M(58)M(59)M(60)M(61)M(62)M(63)\
M(64)M(65)M(66)M(67)M(68)M(69)M(70)M(71)M(72)M(73)M(74)M(75)M(76)M(77)M(78)M(79)\
M(80)M(81)M(82)M(83)M(84)M(85)M(86)M(87)M(88)M(89)M(90)M(91)M(92)M(93)M(94)M(95)\
M(96)M(97)M(98)M(99)

// posenc into named scalars h_0..h_61 (needs x0, x1 in scope)
#define PE(sc, ia, ib, ic, id) { float a0 = x0 * sc, a1 = x1 * sc; \
    h_##ia = sinf(a0); h_##ib = sinf(a1); \
    h_##ic = sinf(a0 + PIO2F); h_##id = sinf(a1 + PIO2F); }
#define POSENC_BODY \
    h_0 = x0; h_1 = x1; \
    PE(1.f,2,3,32,33)      PE(2.f,4,5,34,35)      PE(4.f,6,7,36,37) \
    PE(8.f,8,9,38,39)      PE(16.f,10,11,40,41)   PE(32.f,12,13,42,43) \
    PE(64.f,14,15,44,45)   PE(128.f,16,17,46,47)  PE(256.f,18,19,48,49) \
    PE(512.f,20,21,50,51)  PE(1024.f,22,23,52,53) PE(2048.f,24,25,54,55) \
    PE(4096.f,26,27,56,57) PE(8192.f,28,29,58,59) PE(16384.f,30,31,60,61)

// ---------------- helpers ----------------
__device__ __forceinline__ float silu_f(float v) {
    return v * __builtin_amdgcn_rcpf(1.0f + __expf(-v));
}

__device__ __forceinline__ float wave_sum(float v) {
    #pragma unroll
    for (int off = 1; off < 64; off <<= 1) v += __shfl_xor(v, off, 64);
    return v;
}

// ---------------- kernel 1: posenc, feature-major output H0T[i][p] ----------------
__global__ void posenc_kernel(const float* __restrict__ x, float* __restrict__ H0T) {
    int p = blockIdx.x * 256 + threadIdx.x;
    float x0 = x[2 * p], x1 = x[2 * p + 1];
#define DH(i) float h_##i;
    REP62(DH)
#undef DH
    POSENC_BODY
#define SH(i) H0T[(size_t)(i) * N_PTS + p] = h_##i;
    REP62(SH)
#undef SH
}

// ---------------- kernel 2: hyper-weights wv (4 layers fused) ----------------
__global__ void wv_kernel(
    const float* __restrict__ latent,
    const float* __restrict__ pw0, const float* __restrict__ pb0,
    const float* __restrict__ lnw0, const float* __restrict__ lnb0,
    const float* __restrict__ pw1, const float* __restrict__ pb1,
    const float* __restrict__ lnw1, const float* __restrict__ lnb1,
    const float* __restrict__ pw2, const float* __restrict__ pb2,
    const float* __restrict__ lnw2, const float* __restrict__ lnb2,
    const float* __restrict__ pw3, const float* __restrict__ pb3,
    const float* __restrict__ lnw3, const float* __restrict__ lnb3,
    float* __restrict__ wvb) {
    int blk = blockIdx.x;
    int l = blk >> 8;
    int rest = blk & 255;
    int b = rest >> 4, o = rest & 15;
    int c = threadIdx.x;

    const float *pw, *pb, *lnw, *lnb;
    float* outp;
    int ch;
    switch (l) {
        case 0:  pw = pw0; pb = pb0; lnw = lnw0; lnb = lnb0; outp = wvb;                 ch = 62; break;
        case 1:  pw = pw1; pb = pb1; lnw = lnw1; lnb = lnb1; outp = wvb + 15872;         ch = 16; break;
        case 2:  pw = pw2; pb = pb2; lnw = lnw2; lnb = lnb2; outp = wvb + 15872 + 4096;  ch = 16; break;
        default: pw = pw3; pb = pb3; lnw = lnw3; lnb = lnb3; outp = wvb + 15872 + 8192;  ch = 16; break;
    }
    const float* lat = latent + ((size_t)(b * 64 + l * 16 + o)) * 64;
    float dot = 0.f;
    if (c < ch) {
        const float* pr = pw + ((size_t)(o * ch + c)) * 64;
        #pragma unroll
        for (int d0 = 0; d0 < 64; d0++) dot += lat[d0] * pr[d0];
    }
    float act = (c < ch) ? dot : 0.f;
    float mu = wave_sum(act) * (1.0f / ch);
    float diff = (c < ch) ? (dot - mu) : 0.f;
    float var = wave_sum(diff * diff) * (1.0f / ch);
    float norm = diff * rsqrtf(var + 1e-5f);
    if (c < ch) outp[(size_t)(b * 16 + o) * ch + c] = norm * lnw[c] + lnb[c] + pb[o * ch + c];
}

// ---------------- kernel 3: main per-point MLP, fully scalarized ----------------
template <bool USE_H0>
__global__ __launch_bounds__(256, 3) void main_kernel(
    const float* __restrict__ x, const float* __restrict__ H0T,
    const float* __restrict__ wvb,
    const float* __restrict__ mb0, const float* __restrict__ mb1,
    const float* __restrict__ mb2, const float* __restrict__ mb3,
    const float* __restrict__ w1, const float* __restrict__ b1,
    const float* __restrict__ w2, const float* __restrict__ b2,
    const float* __restrict__ w3, const float* __restrict__ b3,
    float* __restrict__ out) {
    int b = blockIdx.x >> 7;
    int p = ((blockIdx.x & 127) << 8) | threadIdx.x;

#define DH(i) float h_##i;
    REP62(DH)
#undef DH
    if (USE_H0) {
#define LH(i) h_##i = H0T[(size_t)(i) * N_PTS + p];
        REP62(LH)
#undef LH
    } else {
        float x0 = x[2 * p], x1 = x[2 * p + 1];
        POSENC_BODY
    }

    const float* wv0 = wvb + b * 992;                 // [16][62]
    const float* wv1 = wvb + 15872 + b * 256;         // [16][16]
    const float* wv2 = wvb + 15872 + 4096 + b * 256;
    const float* wv3 = wvb + 15872 + 8192 + b * 256;

#define DHA(i) float ha_##i;
    REP16(DHA)
#undef DHA
#define DHB(i) float hb_##i;
    REP16(DHB)
#undef DHB

    // layer 0: h (62) -> ha (16)
#define L0T(i) acc += h_##i * wptr[i];
#define L0(o) { const float* wptr = wv0 + (o) * 62; float acc = mb0[o]; REP62(L0T) ha_##o = silu_f(acc); }
    REP16(L0)
#undef L0

    // layer 1: ha -> hb   (inner terms use REP16I: cannot nest REP16 in REP16)
#define LAT(i) acc += ha_##i * wptr[i];
#define LBT(i) acc += hb_##i * wptr[i];
#define L1(o) { const float* wptr = wv1 + (o) * 16; float acc = mb1[o]; REP16I(LAT) hb_##o = silu_f(acc); }
    REP16(L1)
#undef L1
    // layer 2: hb -> ha
#define L2(o) { const float* wptr = wv2 + (o) * 16; float acc = mb2[o]; REP16I(LBT) ha_##o = silu_f(acc); }
    REP16(L2)
#undef L2
    // layer 3: ha -> hb
#define L3(o) { const float* wptr = wv3 + (o) * 16; float acc = mb3[o]; REP16I(LAT) hb_##o = silu_f(acc); }
    REP16(L3)
#undef L3

    // w1: hb (16) -> h2 (100)
#define DH2(i) float h2_##i;
    REP100(DH2)
#undef DH2
#define W1T(k) acc += hb_##k * wptr[k];
#define W1(i) { const float* wptr = w1 + (i) * 16; float acc = b1[i]; REP16I(W1T) h2_##i = silu_f(acc); }
    REP100(W1)
#undef W1

    // w2 (100x100) fused with w3 (1x100); a4[(j)&3] is constant-indexed -> 4 FMA chains
#define W2T(j) a4[(j) & 3] += h2_##j * wr[(j)];
    float outv = b3[0];
    #pragma unroll 2
    for (int o = 0; o < 100; o++) {
        const float* wr = w2 + o * 100;
        float a4[4];
        a4[0] = b2[o]; a4[1] = 0.f; a4[2] = 0.f; a4[3] = 0.f;
        REP100(W2T)
        outv += silu_f((a4[0] + a4[1]) + (a4[2] + a4[3])) * w3[o];
    }
#undef W2T

    out[(size_t)b * N_PTS + p] = outv;
}

// ---------------- launcher ----------------
extern "C" void kernel_launch(void* const* d_in, const int* in_sizes, int n_in,
                              void* d_out, int out_size, void* d_ws, size_t ws_size,
                              hipStream_t stream) {
    const float* x = (const float*)d_in[0];
    const float* latent = (const float*)d_in[1];
    const float *pw[4], *pb[4], *lnw[4], *lnb[4], *mb[4];
    for (int l = 0; l < 4; l++) {
        pw[l]  = (const float*)d_in[2 + 5 * l];
        pb[l]  = (const float*)d_in[3 + 5 * l];
        lnw[l] = (const float*)d_in[4 + 5 * l];
        lnb[l] = (const float*)d_in[5 + 5 * l];
        mb[l]  = (const float*)d_in[6 + 5 * l];
    }
    const float* w1 = (const float*)d_in[22];
    const float* b1 = (const float*)d_in[23];
    const float* w2 = (const float*)d_in[24];
    const float* b2 = (const float*)d_in[25];
    const float* w3 = (const float*)d_in[26];
    const float* b3 = (const float*)d_in[27];

    float* wsf = (float*)d_ws;
    const size_t H0_FLOATS = (size_t)N_PTS * 62;       // feature-major H0T
    const size_t WV_FLOATS = 15872 + 3 * 4096;
    bool big = ws_size >= (H0_FLOATS + WV_FLOATS) * sizeof(float);

    float* H0T = big ? wsf : nullptr;
    float* wvb = big ? (wsf + H0_FLOATS) : wsf;

    if (big) posenc_kernel<<<128, 256, 0, stream>>>(x, H0T);
    wv_kernel<<<1024, 64, 0, stream>>>(latent,
        pw[0], pb[0], lnw[0], lnb[0],
        pw[1], pb[1], lnw[1], lnb[1],
        pw[2], pb[2], lnw[2], lnb[2],
        pw[3], pb[3], lnw[3], lnb[3],
        wvb);

    dim3 grid(BATCH * (N_PTS / 256));
    if (big) {
        main_kernel<true><<<grid, 256, 0, stream>>>(x, H0T, wvb,
            mb[0], mb[1], mb[2], mb[3], w1, b1, w2, b2, w3, b3, (float*)d_out);
    } else {
        main_kernel<false><<<grid, 256, 0, stream>>>(x, H0T, wvb,
            mb[0], mb[1], mb[2], mb[3], w1, b1, w2, b2, w3, b3, (float*)d_out);
    }
}